// Round 7
// baseline (175.054 us; speedup 1.0000x reference)
//
#include <hip/hip_runtime.h>
#include <hip/hip_bf16.h>
#include <math.h>

// Problem dims
#define Bn 16
#define Sn 128
#define Rn 4
#define Ln 50
#define En 64
#define Hn 64
#define Vn 1000
#define G3 192          // 3*H
#define PH1n 256
#define PH2n 64
#define NSEQ (Bn*Sn*Rn) // 8192
#define NROW (Bn*Sn)    // 2048
#define GP 16           // sequences per block (MFMA M-tile)

typedef short bf16x8 __attribute__((ext_vector_type(8)));
typedef float f32x4  __attribute__((ext_vector_type(4)));

__device__ __forceinline__ unsigned short f2bf(float x) {
    union { float f; unsigned u; } v; v.f = x;
    unsigned r = v.u + 0x7FFF + ((v.u >> 16) & 1);   // RNE
    return (unsigned short)(r >> 16);
}
__device__ __forceinline__ float fsig(float x)  { return 1.0f / (1.0f + __expf(-x)); }
__device__ __forceinline__ float ftanh(float x) { float e = __expf(2.0f * x); return 1.0f - 2.0f / (e + 1.0f); }

// Raw barrier: LDS-drain only; global loads/stores float across (no vmcnt(0)).
#define BAR() do { asm volatile("s_waitcnt lgkmcnt(0)" ::: "memory"); \
                   __builtin_amdgcn_s_barrier(); \
                   __builtin_amdgcn_sched_barrier(0); } while (0)

// ---------------------------------------------------------------------------
// Kernel A: precompute input-projection tables
//   pre[v][j] = bi[j] + sum_e emb[v][e] * Wi[e][j]   (rows 0..63 of Wi)
// ---------------------------------------------------------------------------
__global__ __launch_bounds__(192) void precompute_tab(
    const float* __restrict__ emb,
    const float* __restrict__ Wi_h, const float* __restrict__ bi_h,
    const float* __restrict__ Wi_x, const float* __restrict__ bi_x,
    float* __restrict__ pre_h, float* __restrict__ pre_x)
{
    const int v = blockIdx.x;
    const int j = threadIdx.x;
    const float* Wi = blockIdx.y ? Wi_x : Wi_h;
    const float* bi = blockIdx.y ? bi_x : bi_h;
    float* outp = blockIdx.y ? pre_x : pre_h;
    __shared__ float e_l[En];
    if (j < En) e_l[j] = emb[v * En + j];
    __syncthreads();
    float a = bi[j];
#pragma unroll 8
    for (int k = 0; k < En; ++k) a = fmaf(e_l[k], Wi[k * G3 + j], a);
    outp[v * G3 + j] = a;
}

// ---------------------------------------------------------------------------
// Kernel B: unified MFMA GRU, raw barriers, VGPR budget 128 (min 2 waves/EU).
//   block 0        : intra GRU — M=16 batch sequences, nT=128, h stored every t
//   blocks 1..512  : peer GRU  — M=16 peer sequences,  nT=50, h stored at len-1
// ---------------------------------------------------------------------------
__global__ __launch_bounds__(256, 2) void gru_fused(
    const float* __restrict__ pre_h, const float* __restrict__ pre_x,
    const int*   __restrict__ inter_his, const int* __restrict__ inter_len,
    const float* __restrict__ Wh_h, const float* __restrict__ bh_h,
    const float* __restrict__ Wi_h,
    const int*   __restrict__ intra_x, const float* __restrict__ y,
    const float* __restrict__ Wh_x, const float* __restrict__ bh_x,
    const float* __restrict__ Wi_x,
    float* __restrict__ M_rv, float* __restrict__ h_x)
{
    __shared__ __align__(16) unsigned short h16[2][GP * 64];  // 2 x 2KB, swizzled
    __shared__ int   ids_l[GP][Sn];
    __shared__ float labs_l[GP][Sn];

    const int tid = threadIdx.x;
    const bool isIntra = (blockIdx.x == 0);
    const int nT   = isIntra ? Sn : Ln;
    const int seq0 = isIntra ? 0 : ((int)blockIdx.x - 1) * GP;

    const float* pre = isIntra ? pre_x : pre_h;
    const float* Wh  = isIntra ? Wh_x  : Wh_h;
    const float* bh  = isIntra ? bh_x  : bh_h;
    const float* Wi  = isIntra ? Wi_x  : Wi_h;

    if (isIntra) {
        for (int i = tid; i < GP * Sn; i += 256) {
            int r = i >> 7, t = i & (Sn - 1);
            ids_l[r][t]  = intra_x[r * Sn + t];
            labs_l[r][t] = (t == 0) ? 0.0f : y[r * Sn + t - 1];
        }
    } else {
        for (int i = tid; i < GP * Ln; i += 256) {
            int r = i / Ln, t = i % Ln;
            int base = ((seq0 + r) * Ln + t) * 2;
            ids_l[r][t]  = inter_his[base];
            labs_l[r][t] = (float)inter_his[base + 1];
        }
    }
    for (int i = tid; i < GP * 64; i += 256) h16[0][i] = 0;

    const int lane = tid & 63, w = tid >> 6;
    const int n_ = lane & 15, kb = lane >> 4;
    const int jh = w * 16 + n_;          // this wave's hidden-column

    // B fragments: Wh[64][192] -> 3 gate-tiles x 2 K-halves, bf16, in VGPRs
    bf16x8 bfr[3][2];
#pragma unroll
    for (int g = 0; g < 3; ++g)
#pragma unroll
        for (int kh = 0; kh < 2; ++kh) {
            bf16x8 v;
#pragma unroll
            for (int i = 0; i < 8; ++i)
                v[i] = (short)f2bf(Wh[(kh * 32 + kb * 8 + i) * G3 + g * 64 + jh]);
            bfr[g][kh] = v;
        }
    const float bhr = bh[jh], bhz = bh[64 + jh], bhn = bh[128 + jh];
    const float wlr = Wi[64 * G3 + jh];
    const float wlz = Wi[64 * G3 + 64 + jh];
    const float wln = Wi[64 * G3 + 128 + jh];
    const int rbase = kb * 4;            // C rows (sequences) owned by this lane
    int lenr[4];
#pragma unroll
    for (int q = 0; q < 4; ++q)
        lenr[q] = isIntra ? -1 : inter_len[seq0 + rbase + q];
    float hprev[4] = {0.f, 0.f, 0.f, 0.f};

    // addr(row, bytecol) = row*128 + (bytecol ^ ((row&7)<<4))
    const unsigned arow = (unsigned)(n_ * 128);
    const unsigned ac0  = (unsigned)((kb * 16) ^ ((n_ & 7) << 4));
    const unsigned ac1  = (unsigned)((64 + kb * 16) ^ ((n_ & 7) << 4));
    unsigned woff[4];
#pragma unroll
    for (int q = 0; q < 4; ++q) {
        int r = rbase + q;
        woff[q] = (unsigned)(r * 128 + ((jh * 2) ^ ((r & 7) << 4)));
    }

    // double-buffered input-gather registers (static indexing, rule #20)
    float Ar[4], Az[4], An_[4], Al[4];
    float Br[4], Bz[4], Bn_[4], Bl[4];
#pragma unroll
    for (int q = 0; q < 4; ++q) {
        int id = ids_l[rbase + q][0];
        Al[q] = labs_l[rbase + q][0];
        const float* p = pre + id * G3 + jh;
        Ar[q] = p[0]; Az[q] = p[64]; An_[q] = p[128];
    }
    __syncthreads();   // setup barrier (full drain once, fine)

    auto step = [&](int t, int cur,
                    float (&gr)[4], float (&gz)[4], float (&gn)[4], float (&gl)[4],
                    float (&pr)[4], float (&pz)[4], float (&pn)[4], float (&pl)[4]) {
        const char* rb = (const char*)&h16[cur][0];
        bf16x8 a0 = *(const bf16x8*)(rb + arow + ac0);
        bf16x8 a1 = *(const bf16x8*)(rb + arow + ac1);
        // issue next step's gathers NOW; they complete under counted vmcnt
        // across the raw barrier (no vmcnt(0) drain), hidden by MFMA+gating.
        if (t + 1 < nT) {
#pragma unroll
            for (int q = 0; q < 4; ++q) {
                int id = ids_l[rbase + q][t + 1];
                pl[q] = labs_l[rbase + q][t + 1];
                const float* p = pre + id * G3 + jh;
                pr[q] = p[0]; pz[q] = p[64]; pn[q] = p[128];
            }
        }
        f32x4 z4 = {0.f, 0.f, 0.f, 0.f};
        f32x4 acc0 = __builtin_amdgcn_mfma_f32_16x16x32_bf16(a0, bfr[0][0], z4, 0, 0, 0);
        f32x4 acc1 = __builtin_amdgcn_mfma_f32_16x16x32_bf16(a0, bfr[1][0], z4, 0, 0, 0);
        f32x4 acc2 = __builtin_amdgcn_mfma_f32_16x16x32_bf16(a0, bfr[2][0], z4, 0, 0, 0);
        acc0 = __builtin_amdgcn_mfma_f32_16x16x32_bf16(a1, bfr[0][1], acc0, 0, 0, 0);
        acc1 = __builtin_amdgcn_mfma_f32_16x16x32_bf16(a1, bfr[1][1], acc1, 0, 0, 0);
        acc2 = __builtin_amdgcn_mfma_f32_16x16x32_bf16(a1, bfr[2][1], acc2, 0, 0, 0);

        char* wb = (char*)&h16[cur ^ 1][0];
#pragma unroll
        for (int q = 0; q < 4; ++q) {
            float xr = fmaf(gl[q], wlr, gr[q]);
            float xz = fmaf(gl[q], wlz, gz[q]);
            float xn = fmaf(gl[q], wln, gn[q]);
            float rg = fsig(xr + acc0[q] + bhr);
            float zg = fsig(xz + acc1[q] + bhz);
            float ng = ftanh(fmaf(rg, acc2[q] + bhn, xn));
            float h  = (1.0f - zg) * ng + zg * hprev[q];
            hprev[q] = h;
            *(unsigned short*)(wb + woff[q]) = f2bf(h);
            if (isIntra) {
                h_x[((rbase + q) * Sn + t) * Hn + jh] = h;
            } else if (t == lenr[q] - 1) {
                M_rv[(seq0 + rbase + q) * Hn + jh] = h;
            }
        }
        BAR();   // LDS-drain only; gathers + global stores stay in flight
    };

    for (int t = 0; t < nT; t += 2) {       // nT is even (50 / 128)
        step(t,     0, Ar, Az, An_, Al, Br, Bz, Bn_, Bl);
        step(t + 1, 1, Br, Bz, Bn_, Bl, Ar, Az, An_, Al);
    }
}

// ---------------------------------------------------------------------------
// Kernel C: attention over R peers + output MLP; one (b,s) row per block.
// ---------------------------------------------------------------------------
__global__ __launch_bounds__(256) void attn_mlp(
    const float* __restrict__ h_x, const float* __restrict__ M_rv,
    const float* __restrict__ emb, const int* __restrict__ inter_r,
    const float* __restrict__ y,
    const float* __restrict__ Wq,
    const float* __restrict__ Wo, const float* __restrict__ bo,
    const float* __restrict__ W1, const float* __restrict__ b1,
    const float* __restrict__ W2, const float* __restrict__ b2,
    const float* __restrict__ W3, const float* __restrict__ b3,
    float* __restrict__ out)
{
    const int idx = blockIdx.x;
    const int tid = threadIdx.x;
    __shared__ float sh[64], ql[64], Ml[4][64], scl[4], al[4];
    __shared__ float vv[132], ol[64], z1[PH1n], z2[64];
    __shared__ int   rid[4];
    __shared__ float rlab[4];

    if (tid < 64) sh[tid] = h_x[idx * Hn + tid];
    { int r = tid >> 6, j = tid & 63; Ml[r][j] = M_rv[(idx * Rn + r) * Hn + j]; }
    if (tid < 4) {
        rid[tid]  = inter_r[(idx * Rn + tid) * 2];
        rlab[tid] = (float)inter_r[(idx * Rn + tid) * 2 + 1];
    }
    __syncthreads();
    if (tid < 64) {
        float a = 0.0f;
#pragma unroll 8
        for (int k = 0; k < 64; ++k) a = fmaf(sh[k], Wq[k * Hn + tid], a);
        ql[tid] = a;
    }
    __syncthreads();
    if (tid < 4) {
        float a = 0.0f;
#pragma unroll 8
        for (int k = 0; k < 64; ++k) a = fmaf(ql[k], Ml[tid][k], a);
        scl[tid] = a * 0.125f;
    }
    __syncthreads();
    if (tid == 0) {
        float m = fmaxf(fmaxf(scl[0], scl[1]), fmaxf(scl[2], scl[3]));
        float s = 0.0f, e[4];
#pragma unroll
        for (int r = 0; r < 4; ++r) { e[r] = __expf(scl[r] - m); s += e[r]; }
        float inv = 1.0f / s;
#pragma unroll
        for (int r = 0; r < 4; ++r) al[r] = e[r] * inv;
    }
    __syncthreads();
    if (tid < 129) {
        float a = 0.0f;
#pragma unroll
        for (int r = 0; r < 4; ++r) {
            float val;
            if (tid < 64)       val = Ml[r][tid];
            else if (tid < 128) val = emb[rid[r] * En + (tid - 64)];
            else                val = rlab[r];
            a = fmaf(al[r], val, a);
        }
        vv[tid] = a;
    }
    __syncthreads();
    if (tid < 64) {
        float a = bo[tid];
#pragma unroll 8
        for (int k = 0; k < 64; ++k)  a = fmaf(sh[k], Wo[k * Hn + tid], a);
        for (int k = 0; k < 129; ++k) a = fmaf(vv[k], Wo[(64 + k) * Hn + tid], a);
        ol[tid] = tanhf(a);
    }
    __syncthreads();
    {
        float a0 = 0.f, a1 = 0.f;
#pragma unroll
        for (int k = 0; k < 64; k += 2) {
            a0 = fmaf(ol[k],     W1[k * PH1n + tid],       a0);
            a1 = fmaf(ol[k + 1], W1[(k + 1) * PH1n + tid], a1);
        }
        z1[tid] = fmaxf(b1[tid] + (a0 + a1), 0.0f);
    }
    __syncthreads();
    if (tid < 64) {
        float a0 = 0.f, a1 = 0.f, a2 = 0.f, a3 = 0.f;
#pragma unroll
        for (int k = 0; k < PH1n; k += 4) {
            a0 = fmaf(z1[k],     W2[k * PH2n + tid],       a0);
            a1 = fmaf(z1[k + 1], W2[(k + 1) * PH2n + tid], a1);
            a2 = fmaf(z1[k + 2], W2[(k + 2) * PH2n + tid], a2);
            a3 = fmaf(z1[k + 3], W2[(k + 3) * PH2n + tid], a3);
        }
        z2[tid] = fmaxf(b2[tid] + ((a0 + a1) + (a2 + a3)), 0.0f);
    }
    __syncthreads();
    if (tid == 0) {
        float a = b3[0];
#pragma unroll 8
        for (int k = 0; k < 64; ++k) a = fmaf(z2[k], W3[k], a);
        out[idx] = 1.0f / (1.0f + __expf(-a));
        out[NROW + idx] = y[idx];
    }
}

// ---------------------------------------------------------------------------
extern "C" void kernel_launch(void* const* d_in, const int* in_sizes, int n_in,
                              void* d_out, int out_size, void* d_ws, size_t ws_size,
                              hipStream_t stream) {
    const int*   intra_x   = (const int*)d_in[0];
    const int*   inter_his = (const int*)d_in[1];
    const int*   inter_r   = (const int*)d_in[2];
    const float* y         = (const float*)d_in[3];
    const int*   inter_len = (const int*)d_in[5];
    const float* emb  = (const float*)d_in[6];
    const float* Wi_h = (const float*)d_in[7];
    const float* Wh_h = (const float*)d_in[8];
    const float* bi_h = (const float*)d_in[9];
    const float* bh_h = (const float*)d_in[10];
    const float* Wi_x = (const float*)d_in[11];
    const float* Wh_x = (const float*)d_in[12];
    const float* bi_x = (const float*)d_in[13];
    const float* bh_x = (const float*)d_in[14];
    const float* Wq = (const float*)d_in[15];
    const float* Wo = (const float*)d_in[16];
    const float* bo = (const float*)d_in[17];
    const float* W1 = (const float*)d_in[18];
    const float* b1 = (const float*)d_in[19];
    const float* W2 = (const float*)d_in[20];
    const float* b2 = (const float*)d_in[21];
    const float* W3 = (const float*)d_in[22];
    const float* b3 = (const float*)d_in[23];

    float* out = (float*)d_out;
    float* ws  = (float*)d_ws;
    float* pre_h = ws;                       // 1000*192
    float* pre_x = ws + 192000;              // 1000*192
    float* M_rv  = ws + 384000;              // 8192*64
    float* h_x   = ws + 384000 + 524288;     // 16*128*64

    precompute_tab<<<dim3(Vn, 2), 192, 0, stream>>>(emb, Wi_h, bi_h, Wi_x, bi_x,
                                                    pre_h, pre_x);
    gru_fused<<<1 + NSEQ / GP, 256, 0, stream>>>(pre_h, pre_x, inter_his, inter_len,
                                                 Wh_h, bh_h, Wi_h,
                                                 intra_x, y, Wh_x, bh_x, Wi_x,
                                                 M_rv, h_x);
    attn_mlp<<<NROW, 256, 0, stream>>>(h_x, M_rv, emb, inter_r, y,
                                       Wq, Wo, bo, W1, b1, W2, b2, W3, b3, out);
}

// Round 8
// 124.643 us; speedup vs baseline: 1.4044x; 1.4044x over previous
//
#include <hip/hip_runtime.h>
#include <hip/hip_bf16.h>
#include <math.h>

// Problem dims
#define Bn 16
#define Sn 128
#define Rn 4
#define Ln 50
#define En 64
#define Hn 64
#define Vn 1000
#define G3 192          // 3*H
#define PH1n 256
#define PH2n 64
#define NSEQ (Bn*Sn*Rn) // 8192
#define NROW (Bn*Sn)    // 2048
#define GP 16           // sequences per block (MFMA M-tile)

typedef short bf16x8 __attribute__((ext_vector_type(8)));
typedef float f32x4  __attribute__((ext_vector_type(4)));

__device__ __forceinline__ unsigned short f2bf(float x) {
    union { float f; unsigned u; } v; v.f = x;
    unsigned r = v.u + 0x7FFF + ((v.u >> 16) & 1);   // RNE
    return (unsigned short)(r >> 16);
}
// fast sigmoid/tanh: v_exp_f32 (2^x) + v_rcp_f32, no precise-division chains
__device__ __forceinline__ float fsig(float x) {
    float e = __builtin_amdgcn_exp2f(-x * 1.442695041f);
    return __builtin_amdgcn_rcpf(1.0f + e);
}
__device__ __forceinline__ float ftanh(float x) {
    float e = __builtin_amdgcn_exp2f(x * 2.885390082f);
    return 1.0f - 2.0f * __builtin_amdgcn_rcpf(e + 1.0f);
}

// Raw barrier: LDS-drain only; global loads/stores float across (no vmcnt(0)).
#define BAR() do { asm volatile("s_waitcnt lgkmcnt(0)" ::: "memory"); \
                   __builtin_amdgcn_s_barrier(); \
                   __builtin_amdgcn_sched_barrier(0); } while (0)

// Issue 3 gate-loads for one sequence via un-sinkable volatile asm.
// p[0], p[64], p[128] floats -> offsets 0/256/512 bytes.
__device__ __forceinline__ void gload3(const float* p, float& a, float& b, float& c) {
    asm volatile("global_load_dword %0, %3, off\n\t"
                 "global_load_dword %1, %3, off offset:256\n\t"
                 "global_load_dword %2, %3, off offset:512"
                 : "=&v"(a), "=&v"(b), "=&v"(c) : "v"(p));
}

// ---------------------------------------------------------------------------
// Kernel A: precompute input-projection tables
//   pre[v][j] = bi[j] + sum_e emb[v][e] * Wi[e][j]   (rows 0..63 of Wi)
// ---------------------------------------------------------------------------
__global__ __launch_bounds__(192) void precompute_tab(
    const float* __restrict__ emb,
    const float* __restrict__ Wi_h, const float* __restrict__ bi_h,
    const float* __restrict__ Wi_x, const float* __restrict__ bi_x,
    float* __restrict__ pre_h, float* __restrict__ pre_x)
{
    const int v = blockIdx.x;
    const int j = threadIdx.x;
    const float* Wi = blockIdx.y ? Wi_x : Wi_h;
    const float* bi = blockIdx.y ? bi_x : bi_h;
    float* outp = blockIdx.y ? pre_x : pre_h;
    __shared__ float e_l[En];
    if (j < En) e_l[j] = emb[v * En + j];
    __syncthreads();
    float a = bi[j];
#pragma unroll 8
    for (int k = 0; k < En; ++k) a = fmaf(e_l[k], Wi[k * G3 + j], a);
    outp[v * G3 + j] = a;
}

// ---------------------------------------------------------------------------
// Kernel B: unified MFMA GRU, raw barriers, asm-pinned gather prefetch.
//   block 0        : intra GRU — M=16 batch sequences, nT=128, h stored every t
//   blocks 1..512  : peer GRU  — M=16 peer sequences,  nT=50, h stored at len-1
// ---------------------------------------------------------------------------
__global__ __launch_bounds__(256, 2) void gru_fused(
    const float* __restrict__ pre_h, const float* __restrict__ pre_x,
    const int*   __restrict__ inter_his, const int* __restrict__ inter_len,
    const float* __restrict__ Wh_h, const float* __restrict__ bh_h,
    const float* __restrict__ Wi_h,
    const int*   __restrict__ intra_x, const float* __restrict__ y,
    const float* __restrict__ Wh_x, const float* __restrict__ bh_x,
    const float* __restrict__ Wi_x,
    float* __restrict__ M_rv, float* __restrict__ h_x)
{
    __shared__ __align__(16) unsigned short h16[2][GP * 64];  // 2 x 2KB, swizzled
    __shared__ int   ids_l[GP][Sn];
    __shared__ float labs_l[GP][Sn];

    const int tid = threadIdx.x;
    const bool isIntra = (blockIdx.x == 0);
    const int nT   = isIntra ? Sn : Ln;
    const int seq0 = isIntra ? 0 : ((int)blockIdx.x - 1) * GP;

    const float* pre = isIntra ? pre_x : pre_h;
    const float* Wh  = isIntra ? Wh_x  : Wh_h;
    const float* bh  = isIntra ? bh_x  : bh_h;
    const float* Wi  = isIntra ? Wi_x  : Wi_h;

    if (isIntra) {
        for (int i = tid; i < GP * Sn; i += 256) {
            int r = i >> 7, t = i & (Sn - 1);
            ids_l[r][t]  = intra_x[r * Sn + t];
            labs_l[r][t] = (t == 0) ? 0.0f : y[r * Sn + t - 1];
        }
    } else {
        for (int i = tid; i < GP * Ln; i += 256) {
            int r = i / Ln, t = i % Ln;
            int base = ((seq0 + r) * Ln + t) * 2;
            ids_l[r][t]  = inter_his[base];
            labs_l[r][t] = (float)inter_his[base + 1];
        }
    }
    for (int i = tid; i < GP * 64; i += 256) h16[0][i] = 0;

    const int lane = tid & 63, w = tid >> 6;
    const int n_ = lane & 15, kb = lane >> 4;
    const int jh = w * 16 + n_;          // this wave's hidden-column

    // B fragments: Wh[64][192] -> 3 gate-tiles x 2 K-halves, bf16, in VGPRs
    bf16x8 bfr[3][2];
#pragma unroll
    for (int g = 0; g < 3; ++g)
#pragma unroll
        for (int kh = 0; kh < 2; ++kh) {
            bf16x8 v;
#pragma unroll
            for (int i = 0; i < 8; ++i)
                v[i] = (short)f2bf(Wh[(kh * 32 + kb * 8 + i) * G3 + g * 64 + jh]);
            bfr[g][kh] = v;
        }
    const float bhr = bh[jh], bhz = bh[64 + jh], bhn = bh[128 + jh];
    const float wlr = Wi[64 * G3 + jh];
    const float wlz = Wi[64 * G3 + 64 + jh];
    const float wln = Wi[64 * G3 + 128 + jh];
    const int rbase = kb * 4;            // C rows (sequences) owned by this lane
    int lenr[4];
#pragma unroll
    for (int q = 0; q < 4; ++q)
        lenr[q] = isIntra ? -1 : inter_len[seq0 + rbase + q];
    float hprev[4] = {0.f, 0.f, 0.f, 0.f};

    // addr(row, bytecol) = row*128 + (bytecol ^ ((row&7)<<4))
    const unsigned arow = (unsigned)(n_ * 128);
    const unsigned ac0  = (unsigned)((kb * 16) ^ ((n_ & 7) << 4));
    const unsigned ac1  = (unsigned)((64 + kb * 16) ^ ((n_ & 7) << 4));
    unsigned woff[4];
#pragma unroll
    for (int q = 0; q < 4; ++q) {
        int r = rbase + q;
        woff[q] = (unsigned)(r * 128 + ((jh * 2) ^ ((r & 7) << 4)));
    }

    // double-buffered gather registers; loads pinned in asm (can't be sunk)
    float Ar[4], Az[4], An_[4], Al[4];
    float Br[4], Bz[4], Bn_[4], Bl[4];
#pragma unroll
    for (int q = 0; q < 4; ++q) {
        int id = ids_l[rbase + q][0];
        Al[q] = labs_l[rbase + q][0];
        gload3(pre + id * G3 + jh, Ar[q], Az[q], An_[q]);
    }
    __syncthreads();   // setup barrier (full drain once: prologue loads land)

    auto step = [&](int t, int cur,
                    float (&gr)[4], float (&gz)[4], float (&gn)[4], float (&gl)[4],
                    float (&pr)[4], float (&pz)[4], float (&pn)[4], float (&pl)[4]) {
        const char* rb = (const char*)&h16[cur][0];
        bf16x8 a0 = *(const bf16x8*)(rb + arow + ac0);
        bf16x8 a1 = *(const bf16x8*)(rb + arow + ac1);
        // issue next step's 12 gathers NOW (volatile asm: cannot be sunk);
        // uniform count every step so the vmcnt below is exact.
        const int tn = (t + 1 < nT) ? t + 1 : t;
#pragma unroll
        for (int q = 0; q < 4; ++q) {
            int id = ids_l[rbase + q][tn];
            pl[q] = labs_l[rbase + q][tn];
            gload3(pre + id * G3 + jh, pr[q], pz[q], pn[q]);
        }
        f32x4 z4 = {0.f, 0.f, 0.f, 0.f};
        f32x4 acc0 = __builtin_amdgcn_mfma_f32_16x16x32_bf16(a0, bfr[0][0], z4, 0, 0, 0);
        f32x4 acc1 = __builtin_amdgcn_mfma_f32_16x16x32_bf16(a0, bfr[1][0], z4, 0, 0, 0);
        f32x4 acc2 = __builtin_amdgcn_mfma_f32_16x16x32_bf16(a0, bfr[2][0], z4, 0, 0, 0);
        acc0 = __builtin_amdgcn_mfma_f32_16x16x32_bf16(a1, bfr[0][1], acc0, 0, 0, 0);
        acc1 = __builtin_amdgcn_mfma_f32_16x16x32_bf16(a1, bfr[1][1], acc1, 0, 0, 0);
        acc2 = __builtin_amdgcn_mfma_f32_16x16x32_bf16(a1, bfr[2][1], acc2, 0, 0, 0);

        // wait: everything older than the 12 just-issued loads is complete,
        // i.e. the PREVIOUS step's gathers (gr/gz/gn) have landed.
        asm volatile("s_waitcnt vmcnt(12)" ::: "memory");
        __builtin_amdgcn_sched_barrier(0);

        char* wb = (char*)&h16[cur ^ 1][0];
#pragma unroll
        for (int q = 0; q < 4; ++q) {
            float xr = fmaf(gl[q], wlr, gr[q]);
            float xz = fmaf(gl[q], wlz, gz[q]);
            float xn = fmaf(gl[q], wln, gn[q]);
            float rg = fsig(xr + acc0[q] + bhr);
            float zg = fsig(xz + acc1[q] + bhz);
            float ng = ftanh(fmaf(rg, acc2[q] + bhn, xn));
            float h  = (1.0f - zg) * ng + zg * hprev[q];
            hprev[q] = h;
            *(unsigned short*)(wb + woff[q]) = f2bf(h);
            if (isIntra) {
                h_x[((rbase + q) * Sn + t) * Hn + jh] = h;
            } else if (t == lenr[q] - 1) {
                M_rv[(seq0 + rbase + q) * Hn + jh] = h;
            }
        }
        BAR();   // LDS-drain only; gathers + global stores stay in flight
    };

    for (int t = 0; t < nT; t += 2) {       // nT is even (50 / 128)
        step(t,     0, Ar, Az, An_, Al, Br, Bz, Bn_, Bl);
        step(t + 1, 1, Br, Bz, Bn_, Bl, Ar, Az, An_, Al);
    }
}

// ---------------------------------------------------------------------------
// Kernel C: attention over R peers + output MLP; one (b,s) row per block.
// ---------------------------------------------------------------------------
__global__ __launch_bounds__(256) void attn_mlp(
    const float* __restrict__ h_x, const float* __restrict__ M_rv,
    const float* __restrict__ emb, const int* __restrict__ inter_r,
    const float* __restrict__ y,
    const float* __restrict__ Wq,
    const float* __restrict__ Wo, const float* __restrict__ bo,
    const float* __restrict__ W1, const float* __restrict__ b1,
    const float* __restrict__ W2, const float* __restrict__ b2,
    const float* __restrict__ W3, const float* __restrict__ b3,
    float* __restrict__ out)
{
    const int idx = blockIdx.x;
    const int tid = threadIdx.x;
    __shared__ float sh[64], ql[64], Ml[4][64], scl[4], al[4];
    __shared__ float vv[132], ol[64], z1[PH1n], z2[64];
    __shared__ int   rid[4];
    __shared__ float rlab[4];

    if (tid < 64) sh[tid] = h_x[idx * Hn + tid];
    { int r = tid >> 6, j = tid & 63; Ml[r][j] = M_rv[(idx * Rn + r) * Hn + j]; }
    if (tid < 4) {
        rid[tid]  = inter_r[(idx * Rn + tid) * 2];
        rlab[tid] = (float)inter_r[(idx * Rn + tid) * 2 + 1];
    }
    __syncthreads();
    if (tid < 64) {
        float a = 0.0f;
#pragma unroll 8
        for (int k = 0; k < 64; ++k) a = fmaf(sh[k], Wq[k * Hn + tid], a);
        ql[tid] = a;
    }
    __syncthreads();
    if (tid < 4) {
        float a = 0.0f;
#pragma unroll 8
        for (int k = 0; k < 64; ++k) a = fmaf(ql[k], Ml[tid][k], a);
        scl[tid] = a * 0.125f;
    }
    __syncthreads();
    if (tid == 0) {
        float m = fmaxf(fmaxf(scl[0], scl[1]), fmaxf(scl[2], scl[3]));
        float s = 0.0f, e[4];
#pragma unroll
        for (int r = 0; r < 4; ++r) { e[r] = __expf(scl[r] - m); s += e[r]; }
        float inv = 1.0f / s;
#pragma unroll
        for (int r = 0; r < 4; ++r) al[r] = e[r] * inv;
    }
    __syncthreads();
    if (tid < 129) {
        float a = 0.0f;
#pragma unroll
        for (int r = 0; r < 4; ++r) {
            float val;
            if (tid < 64)       val = Ml[r][tid];
            else if (tid < 128) val = emb[rid[r] * En + (tid - 64)];
            else                val = rlab[r];
            a = fmaf(al[r], val, a);
        }
        vv[tid] = a;
    }
    __syncthreads();
    if (tid < 64) {
        float a = bo[tid];
#pragma unroll 8
        for (int k = 0; k < 64; ++k)  a = fmaf(sh[k], Wo[k * Hn + tid], a);
        for (int k = 0; k < 129; ++k) a = fmaf(vv[k], Wo[(64 + k) * Hn + tid], a);
        ol[tid] = tanhf(a);
    }
    __syncthreads();
    {
        float a0 = 0.f, a1 = 0.f;
#pragma unroll
        for (int k = 0; k < 64; k += 2) {
            a0 = fmaf(ol[k],     W1[k * PH1n + tid],       a0);
            a1 = fmaf(ol[k + 1], W1[(k + 1) * PH1n + tid], a1);
        }
        z1[tid] = fmaxf(b1[tid] + (a0 + a1), 0.0f);
    }
    __syncthreads();
    if (tid < 64) {
        float a0 = 0.f, a1 = 0.f, a2 = 0.f, a3 = 0.f;
#pragma unroll
        for (int k = 0; k < PH1n; k += 4) {
            a0 = fmaf(z1[k],     W2[k * PH2n + tid],       a0);
            a1 = fmaf(z1[k + 1], W2[(k + 1) * PH2n + tid], a1);
            a2 = fmaf(z1[k + 2], W2[(k + 2) * PH2n + tid], a2);
            a3 = fmaf(z1[k + 3], W2[(k + 3) * PH2n + tid], a3);
        }
        z2[tid] = fmaxf(b2[tid] + ((a0 + a1) + (a2 + a3)), 0.0f);
    }
    __syncthreads();
    if (tid == 0) {
        float a = b3[0];
#pragma unroll 8
        for (int k = 0; k < 64; ++k) a = fmaf(z2[k], W3[k], a);
        out[idx] = 1.0f / (1.0f + __expf(-a));
        out[NROW + idx] = y[idx];
    }
}

// ---------------------------------------------------------------------------
extern "C" void kernel_launch(void* const* d_in, const int* in_sizes, int n_in,
                              void* d_out, int out_size, void* d_ws, size_t ws_size,
                              hipStream_t stream) {
    const int*   intra_x   = (const int*)d_in[0];
    const int*   inter_his = (const int*)d_in[1];
    const int*   inter_r   = (const int*)d_in[2];
    const float* y         = (const float*)d_in[3];
    const int*   inter_len = (const int*)d_in[5];
    const float* emb  = (const float*)d_in[6];
    const float* Wi_h = (const float*)d_in[7];
    const float* Wh_h = (const float*)d_in[8];
    const float* bi_h = (const float*)d_in[9];
    const float* bh_h = (const float*)d_in[10];
    const float* Wi_x = (const float*)d_in[11];
    const float* Wh_x = (const float*)d_in[12];
    const float* bi_x = (const float*)d_in[13];
    const float* bh_x = (const float*)d_in[14];
    const float* Wq = (const float*)d_in[15];
    const float* Wo = (const float*)d_in[16];
    const float* bo = (const float*)d_in[17];
    const float* W1 = (const float*)d_in[18];
    const float* b1 = (const float*)d_in[19];
    const float* W2 = (const float*)d_in[20];
    const float* b2 = (const float*)d_in[21];
    const float* W3 = (const float*)d_in[22];
    const float* b3 = (const float*)d_in[23];

    float* out = (float*)d_out;
    float* ws  = (float*)d_ws;
    float* pre_h = ws;                       // 1000*192
    float* pre_x = ws + 192000;              // 1000*192
    float* M_rv  = ws + 384000;              // 8192*64
    float* h_x   = ws + 384000 + 524288;     // 16*128*64

    precompute_tab<<<dim3(Vn, 2), 192, 0, stream>>>(emb, Wi_h, bi_h, Wi_x, bi_x,
                                                    pre_h, pre_x);
    gru_fused<<<1 + NSEQ / GP, 256, 0, stream>>>(pre_h, pre_x, inter_his, inter_len,
                                                 Wh_h, bh_h, Wi_h,
                                                 intra_x, y, Wh_x, bh_x, Wi_x,
                                                 M_rv, h_x);
    attn_mlp<<<NROW, 256, 0, stream>>>(h_x, M_rv, emb, inter_r, y,
                                       Wq, Wo, bo, W1, b1, W2, b2, W3, b3, out);
}

// Round 9
// 106.097 us; speedup vs baseline: 1.6499x; 1.1748x over previous
//
#include <hip/hip_runtime.h>
#include <hip/hip_bf16.h>
#include <math.h>

// Problem dims
#define Bn 16
#define Sn 128
#define Rn 4
#define Ln 50
#define En 64
#define Hn 64
#define Vn 1000
#define G3 192          // 3*H
#define PH1n 256
#define PH2n 64
#define NSEQ (Bn*Sn*Rn) // 8192
#define NROW (Bn*Sn)    // 2048
#define GP 16           // sequences per block (MFMA M-tile)

typedef short bf16x8 __attribute__((ext_vector_type(8)));
typedef float f32x4  __attribute__((ext_vector_type(4)));

__device__ __forceinline__ unsigned short f2bf(float x) {
    union { float f; unsigned u; } v; v.f = x;
    unsigned r = v.u + 0x7FFF + ((v.u >> 16) & 1);   // RNE
    return (unsigned short)(r >> 16);
}
__device__ __forceinline__ float bf2f(unsigned short b) {
    union { unsigned u; float f; } v; v.u = ((unsigned)b) << 16; return v.f;
}
// packed fp32->bf16 pair (RNE), 1 instruction
__device__ __forceinline__ unsigned cvtpk_bf16(float lo, float hi) {
    unsigned r;
    asm volatile("v_cvt_pk_bf16_f32 %0, %1, %2" : "=v"(r) : "v"(lo), "v"(hi));
    return r;
}
// fast sigmoid/tanh: v_exp_f32 (2^x) + v_rcp_f32, no precise-division chains
__device__ __forceinline__ float fsig(float x) {
    float e = __builtin_amdgcn_exp2f(-x * 1.442695041f);
    return __builtin_amdgcn_rcpf(1.0f + e);
}
__device__ __forceinline__ float ftanh(float x) {
    float e = __builtin_amdgcn_exp2f(x * 2.885390082f);
    return 1.0f - 2.0f * __builtin_amdgcn_rcpf(e + 1.0f);
}

// Raw barrier: LDS-drain only; global loads/stores float across (no vmcnt(0)).
#define BAR() do { asm volatile("s_waitcnt lgkmcnt(0)" ::: "memory"); \
                   __builtin_amdgcn_s_barrier(); \
                   __builtin_amdgcn_sched_barrier(0); } while (0)

// Issue 3 gate-loads for one sequence via un-sinkable volatile asm.
// p[0], p[64], p[128] floats -> offsets 0/256/512 bytes.
__device__ __forceinline__ void gload3(const float* p, float& a, float& b, float& c) {
    asm volatile("global_load_dword %0, %3, off\n\t"
                 "global_load_dword %1, %3, off offset:256\n\t"
                 "global_load_dword %2, %3, off offset:512"
                 : "=&v"(a), "=&v"(b), "=&v"(c) : "v"(p));
}

// ---------------------------------------------------------------------------
// Kernel A: blocks [0, Vn)       : pre_h[v][j] = bi_h[j] + emb[v]·Wi_h[:,j]
//           blocks [Vn, Vn+NROW) : xw[row][j]  = bi_x[j] + emb[id]·Wi_x[:,j]
//                                  + y_sh·Wi_x[64,j]   (intra inputs, linear)
// ---------------------------------------------------------------------------
__global__ __launch_bounds__(192) void precompute_tab(
    const float* __restrict__ emb,
    const float* __restrict__ Wi_h, const float* __restrict__ bi_h,
    const float* __restrict__ Wi_x, const float* __restrict__ bi_x,
    const int*   __restrict__ intra_x, const float* __restrict__ y,
    float* __restrict__ pre_h, float* __restrict__ xw)
{
    const int bx = blockIdx.x;
    const int j = threadIdx.x;            // 0..191
    __shared__ float e_l[En];
    if (bx < Vn) {
        if (j < En) e_l[j] = emb[bx * En + j];
        __syncthreads();
        float a = bi_h[j];
#pragma unroll 8
        for (int k = 0; k < En; ++k) a = fmaf(e_l[k], Wi_h[k * G3 + j], a);
        pre_h[bx * G3 + j] = a;
    } else {
        const int row = bx - Vn;          // row = b*Sn + t
        const int id = intra_x[row];
        const float lb = (row & (Sn - 1)) ? y[row - 1] : 0.0f;
        if (j < En) e_l[j] = emb[id * En + j];
        __syncthreads();
        float a = bi_x[j];
#pragma unroll 8
        for (int k = 0; k < En; ++k) a = fmaf(e_l[k], Wi_x[k * G3 + j], a);
        a = fmaf(lb, Wi_x[64 * G3 + j], a);
        xw[row * G3 + j] = a;
    }
}

// ---------------------------------------------------------------------------
// Kernel B: unified MFMA GRU, raw barriers, asm-pinned gather prefetch.
//   block 0        : intra GRU — M=16 batch sequences, nT=128, linear xw reads
//   blocks 1..512  : peer GRU  — M=16 peer sequences,  nT=50, pre_h gathers
// ---------------------------------------------------------------------------
__global__ __launch_bounds__(256, 2) void gru_fused(
    const float* __restrict__ pre_h, const float* __restrict__ xw,
    const int*   __restrict__ inter_his, const int* __restrict__ inter_len,
    const float* __restrict__ Wh_h, const float* __restrict__ bh_h,
    const float* __restrict__ Wi_h,
    const float* __restrict__ Wh_x, const float* __restrict__ bh_x,
    unsigned short* __restrict__ mrv16, float* __restrict__ h_x)
{
    __shared__ __align__(16) unsigned short h16[2][GP * 64];  // 2 x 2KB, swizzled
    __shared__ int   ids_l[GP][Ln];
    __shared__ float labs_l[GP][Ln];

    const int tid = threadIdx.x;
    const int lane = tid & 63, w = tid >> 6;
    const int n_ = lane & 15, kb = lane >> 4;
    const int jh = w * 16 + n_;          // this wave's hidden-column
    const int rbase = kb * 4;            // C rows (sequences) owned by this lane

    // addr(row, bytecol) = row*128 + (bytecol ^ ((row&7)<<4))
    const unsigned arow = (unsigned)(n_ * 128);
    const unsigned ac0  = (unsigned)((kb * 16) ^ ((n_ & 7) << 4));
    const unsigned ac1  = (unsigned)((64 + kb * 16) ^ ((n_ & 7) << 4));
    unsigned woff[4];
#pragma unroll
    for (int q = 0; q < 4; ++q) {
        int r = rbase + q;
        woff[q] = (unsigned)(r * 128 + ((jh * 2) ^ ((r & 7) << 4)));
    }
    for (int i = tid; i < GP * 64; i += 256) h16[0][i] = 0;

    if (blockIdx.x != 0) {
        // =============== PEER GRU ===============
        const int seq0 = ((int)blockIdx.x - 1) * GP;
        for (int i = tid; i < GP * Ln; i += 256) {
            int r = i / Ln, t = i % Ln;
            int base = ((seq0 + r) * Ln + t) * 2;
            ids_l[r][t]  = inter_his[base];
            labs_l[r][t] = (float)inter_his[base + 1];
        }
        // B fragments: Wh_h[64][192] -> 3 gate-tiles x 2 K-halves in regs
        bf16x8 bfr[3][2];
#pragma unroll
        for (int g = 0; g < 3; ++g)
#pragma unroll
            for (int kh = 0; kh < 2; ++kh) {
                bf16x8 v;
#pragma unroll
                for (int i = 0; i < 8; ++i)
                    v[i] = (short)f2bf(Wh_h[(kh * 32 + kb * 8 + i) * G3 + g * 64 + jh]);
                bfr[g][kh] = v;
            }
        const float bhr = bh_h[jh], bhz = bh_h[64 + jh], bhn = bh_h[128 + jh];
        const float wlr = Wi_h[64 * G3 + jh];
        const float wlz = Wi_h[64 * G3 + 64 + jh];
        const float wln = Wi_h[64 * G3 + 128 + jh];
        int lenr[4];
#pragma unroll
        for (int q = 0; q < 4; ++q) lenr[q] = inter_len[seq0 + rbase + q];
        float hprev[4] = {0.f, 0.f, 0.f, 0.f};

        float Ar[4], Az[4], An_[4], Al[4];
        float Br[4], Bz[4], Bn_[4], Bl[4];
#pragma unroll
        for (int q = 0; q < 4; ++q) {
            int id = ids_l[rbase + q][0];
            Al[q] = labs_l[rbase + q][0];
            gload3(pre_h + id * G3 + jh, Ar[q], Az[q], An_[q]);
        }
        __syncthreads();   // setup barrier (full drain once: prologue loads land)

        auto step = [&](int t, int cur,
                        float (&gr)[4], float (&gz)[4], float (&gn)[4], float (&gl)[4],
                        float (&pr)[4], float (&pz)[4], float (&pn)[4], float (&pl)[4]) {
            const char* rb = (const char*)&h16[cur][0];
            bf16x8 a0 = *(const bf16x8*)(rb + arow + ac0);
            bf16x8 a1 = *(const bf16x8*)(rb + arow + ac1);
            const int tn = (t + 1 < Ln) ? t + 1 : t;
#pragma unroll
            for (int q = 0; q < 4; ++q) {
                int id = ids_l[rbase + q][tn];
                pl[q] = labs_l[rbase + q][tn];
                gload3(pre_h + id * G3 + jh, pr[q], pz[q], pn[q]);
            }
            f32x4 z4 = {0.f, 0.f, 0.f, 0.f};
            f32x4 acc0 = __builtin_amdgcn_mfma_f32_16x16x32_bf16(a0, bfr[0][0], z4, 0, 0, 0);
            f32x4 acc1 = __builtin_amdgcn_mfma_f32_16x16x32_bf16(a0, bfr[1][0], z4, 0, 0, 0);
            f32x4 acc2 = __builtin_amdgcn_mfma_f32_16x16x32_bf16(a0, bfr[2][0], z4, 0, 0, 0);
            acc0 = __builtin_amdgcn_mfma_f32_16x16x32_bf16(a1, bfr[0][1], acc0, 0, 0, 0);
            acc1 = __builtin_amdgcn_mfma_f32_16x16x32_bf16(a1, bfr[1][1], acc1, 0, 0, 0);
            acc2 = __builtin_amdgcn_mfma_f32_16x16x32_bf16(a1, bfr[2][1], acc2, 0, 0, 0);

            asm volatile("s_waitcnt vmcnt(12)" ::: "memory");
            __builtin_amdgcn_sched_barrier(0);

            char* wb = (char*)&h16[cur ^ 1][0];
            float hn[4];
#pragma unroll
            for (int q = 0; q < 4; ++q) {
                float xr = fmaf(gl[q], wlr, gr[q]);
                float xz = fmaf(gl[q], wlz, gz[q]);
                float xn = fmaf(gl[q], wln, gn[q]);
                float rg = fsig(xr + acc0[q] + bhr);
                float zg = fsig(xz + acc1[q] + bhz);
                float ng = ftanh(fmaf(rg, acc2[q] + bhn, xn));
                float h  = (1.0f - zg) * ng + zg * hprev[q];
                hprev[q] = h; hn[q] = h;
                if (t == lenr[q] - 1)
                    mrv16[(seq0 + rbase + q) * Hn + jh] = f2bf(h);
            }
            unsigned u01 = cvtpk_bf16(hn[0], hn[1]);
            unsigned u23 = cvtpk_bf16(hn[2], hn[3]);
            *(unsigned short*)(wb + woff[0]) = (unsigned short)u01;
            *(unsigned short*)(wb + woff[1]) = (unsigned short)(u01 >> 16);
            *(unsigned short*)(wb + woff[2]) = (unsigned short)u23;
            *(unsigned short*)(wb + woff[3]) = (unsigned short)(u23 >> 16);
            BAR();   // LDS-drain only; gathers + global stores stay in flight
        };

        for (int t = 0; t < Ln; t += 2) {
            step(t,     0, Ar, Az, An_, Al, Br, Bz, Bn_, Bl);
            step(t + 1, 1, Br, Bz, Bn_, Bl, Ar, Az, An_, Al);
        }
    } else {
        // =============== INTRA GRU (linear xw reads) ===============
        bf16x8 bfr[3][2];
#pragma unroll
        for (int g = 0; g < 3; ++g)
#pragma unroll
            for (int kh = 0; kh < 2; ++kh) {
                bf16x8 v;
#pragma unroll
                for (int i = 0; i < 8; ++i)
                    v[i] = (short)f2bf(Wh_x[(kh * 32 + kb * 8 + i) * G3 + g * 64 + jh]);
                bfr[g][kh] = v;
            }
        const float bhr = bh_x[jh], bhz = bh_x[64 + jh], bhn = bh_x[128 + jh];
        float hprev[4] = {0.f, 0.f, 0.f, 0.f};

        // per-sequence input pointers (advance by G3 per step) + h_x outputs
        const float* q0 = xw + (rbase + 0) * Sn * G3 + jh;
        const float* q1 = xw + (rbase + 1) * Sn * G3 + jh;
        const float* q2 = xw + (rbase + 2) * Sn * G3 + jh;
        const float* q3 = xw + (rbase + 3) * Sn * G3 + jh;
        float* p0 = h_x + (rbase + 0) * Sn * Hn + jh;
        float* p1 = h_x + (rbase + 1) * Sn * Hn + jh;
        float* p2 = h_x + (rbase + 2) * Sn * Hn + jh;
        float* p3 = h_x + (rbase + 3) * Sn * Hn + jh;

        float Ar[4], Az[4], An_[4];
        float Br[4], Bz[4], Bn_[4];
        gload3(q0, Ar[0], Az[0], An_[0]);
        gload3(q1, Ar[1], Az[1], An_[1]);
        gload3(q2, Ar[2], Az[2], An_[2]);
        gload3(q3, Ar[3], Az[3], An_[3]);
        __syncthreads();   // h16[0] zeros visible + prologue loads drained

        auto istep = [&](int t, int cur,
                         float (&gr)[4], float (&gz)[4], float (&gn)[4],
                         float (&pr)[4], float (&pz)[4], float (&pn)[4]) {
            const char* rb = (const char*)&h16[cur][0];
            bf16x8 a0 = *(const bf16x8*)(rb + arow + ac0);
            bf16x8 a1 = *(const bf16x8*)(rb + arow + ac1);
            if (t + 1 < Sn) { q0 += G3; q1 += G3; q2 += G3; q3 += G3; }
            gload3(q0, pr[0], pz[0], pn[0]);   // 12 loads every step (uniform
            gload3(q1, pr[1], pz[1], pn[1]);   // vmcnt; last step reloads t)
            gload3(q2, pr[2], pz[2], pn[2]);
            gload3(q3, pr[3], pz[3], pn[3]);
            f32x4 z4 = {0.f, 0.f, 0.f, 0.f};
            f32x4 acc0 = __builtin_amdgcn_mfma_f32_16x16x32_bf16(a0, bfr[0][0], z4, 0, 0, 0);
            f32x4 acc1 = __builtin_amdgcn_mfma_f32_16x16x32_bf16(a0, bfr[1][0], z4, 0, 0, 0);
            f32x4 acc2 = __builtin_amdgcn_mfma_f32_16x16x32_bf16(a0, bfr[2][0], z4, 0, 0, 0);
            acc0 = __builtin_amdgcn_mfma_f32_16x16x32_bf16(a1, bfr[0][1], acc0, 0, 0, 0);
            acc1 = __builtin_amdgcn_mfma_f32_16x16x32_bf16(a1, bfr[1][1], acc1, 0, 0, 0);
            acc2 = __builtin_amdgcn_mfma_f32_16x16x32_bf16(a1, bfr[2][1], acc2, 0, 0, 0);

            asm volatile("s_waitcnt vmcnt(12)" ::: "memory");
            __builtin_amdgcn_sched_barrier(0);

            char* wb = (char*)&h16[cur ^ 1][0];
            float hn[4];
#pragma unroll
            for (int q = 0; q < 4; ++q) {
                float rg = fsig(gr[q] + acc0[q] + bhr);
                float zg = fsig(gz[q] + acc1[q] + bhz);
                float ng = ftanh(fmaf(rg, acc2[q] + bhn, gn[q]));
                float h  = (1.0f - zg) * ng + zg * hprev[q];
                hprev[q] = h; hn[q] = h;
            }
            unsigned u01 = cvtpk_bf16(hn[0], hn[1]);
            unsigned u23 = cvtpk_bf16(hn[2], hn[3]);
            *(unsigned short*)(wb + woff[0]) = (unsigned short)u01;
            *(unsigned short*)(wb + woff[1]) = (unsigned short)(u01 >> 16);
            *(unsigned short*)(wb + woff[2]) = (unsigned short)u23;
            *(unsigned short*)(wb + woff[3]) = (unsigned short)(u23 >> 16);
            *p0 = hn[0]; p0 += Hn;
            *p1 = hn[1]; p1 += Hn;
            *p2 = hn[2]; p2 += Hn;
            *p3 = hn[3]; p3 += Hn;
            BAR();
        };

        for (int t = 0; t < Sn; t += 2) {
            istep(t,     0, Ar, Az, An_, Br, Bz, Bn_);
            istep(t + 1, 1, Br, Bz, Bn_, Ar, Az, An_);
        }
    }
}

// ---------------------------------------------------------------------------
// Kernel C: attention over R peers + output MLP; one (b,s) row per block.
// ---------------------------------------------------------------------------
__global__ __launch_bounds__(256) void attn_mlp(
    const float* __restrict__ h_x, const unsigned short* __restrict__ mrv16,
    const float* __restrict__ emb, const int* __restrict__ inter_r,
    const float* __restrict__ y,
    const float* __restrict__ Wq,
    const float* __restrict__ Wo, const float* __restrict__ bo,
    const float* __restrict__ W1, const float* __restrict__ b1,
    const float* __restrict__ W2, const float* __restrict__ b2,
    const float* __restrict__ W3, const float* __restrict__ b3,
    float* __restrict__ out)
{
    const int idx = blockIdx.x;
    const int tid = threadIdx.x;
    __shared__ float sh[64], ql[64], Ml[4][64], scl[4], al[4];
    __shared__ float vv[132], ol[64], z1[PH1n], z2[64];
    __shared__ int   rid[4];
    __shared__ float rlab[4];

    if (tid < 64) sh[tid] = h_x[idx * Hn + tid];
    { int r = tid >> 6, j = tid & 63; Ml[r][j] = bf2f(mrv16[(idx * Rn + r) * Hn + j]); }
    if (tid < 4) {
        rid[tid]  = inter_r[(idx * Rn + tid) * 2];
        rlab[tid] = (float)inter_r[(idx * Rn + tid) * 2 + 1];
    }
    __syncthreads();
    if (tid < 64) {
        float a = 0.0f;
#pragma unroll 8
        for (int k = 0; k < 64; ++k) a = fmaf(sh[k], Wq[k * Hn + tid], a);
        ql[tid] = a;
    }
    __syncthreads();
    if (tid < 4) {
        float a = 0.0f;
#pragma unroll 8
        for (int k = 0; k < 64; ++k) a = fmaf(ql[k], Ml[tid][k], a);
        scl[tid] = a * 0.125f;
    }
    __syncthreads();
    if (tid == 0) {
        float m = fmaxf(fmaxf(scl[0], scl[1]), fmaxf(scl[2], scl[3]));
        float s = 0.0f, e[4];
#pragma unroll
        for (int r = 0; r < 4; ++r) { e[r] = __expf(scl[r] - m); s += e[r]; }
        float inv = 1.0f / s;
#pragma unroll
        for (int r = 0; r < 4; ++r) al[r] = e[r] * inv;
    }
    __syncthreads();
    if (tid < 129) {
        float a = 0.0f;
#pragma unroll
        for (int r = 0; r < 4; ++r) {
            float val;
            if (tid < 64)       val = Ml[r][tid];
            else if (tid < 128) val = emb[rid[r] * En + (tid - 64)];
            else                val = rlab[r];
            a = fmaf(al[r], val, a);
        }
        vv[tid] = a;
    }
    __syncthreads();
    if (tid < 64) {
        float a = bo[tid];
#pragma unroll 8
        for (int k = 0; k < 64; ++k)  a = fmaf(sh[k], Wo[k * Hn + tid], a);
        for (int k = 0; k < 129; ++k) a = fmaf(vv[k], Wo[(64 + k) * Hn + tid], a);
        ol[tid] = tanhf(a);
    }
    __syncthreads();
    {
        float a0 = 0.f, a1 = 0.f;
#pragma unroll
        for (int k = 0; k < 64; k += 2) {
            a0 = fmaf(ol[k],     W1[k * PH1n + tid],       a0);
            a1 = fmaf(ol[k + 1], W1[(k + 1) * PH1n + tid], a1);
        }
        z1[tid] = fmaxf(b1[tid] + (a0 + a1), 0.0f);
    }
    __syncthreads();
    if (tid < 64) {
        float a0 = 0.f, a1 = 0.f, a2 = 0.f, a3 = 0.f;
#pragma unroll
        for (int k = 0; k < PH1n; k += 4) {
            a0 = fmaf(z1[k],     W2[k * PH2n + tid],       a0);
            a1 = fmaf(z1[k + 1], W2[(k + 1) * PH2n + tid], a1);
            a2 = fmaf(z1[k + 2], W2[(k + 2) * PH2n + tid], a2);
            a3 = fmaf(z1[k + 3], W2[(k + 3) * PH2n + tid], a3);
        }
        z2[tid] = fmaxf(b2[tid] + ((a0 + a1) + (a2 + a3)), 0.0f);
    }
    __syncthreads();
    if (tid == 0) {
        float a = b3[0];
#pragma unroll 8
        for (int k = 0; k < 64; ++k) a = fmaf(z2[k], W3[k], a);
        out[idx] = 1.0f / (1.0f + __expf(-a));
        out[NROW + idx] = y[idx];
    }
}

// ---------------------------------------------------------------------------
extern "C" void kernel_launch(void* const* d_in, const int* in_sizes, int n_in,
                              void* d_out, int out_size, void* d_ws, size_t ws_size,
                              hipStream_t stream) {
    const int*   intra_x   = (const int*)d_in[0];
    const int*   inter_his = (const int*)d_in[1];
    const int*   inter_r   = (const int*)d_in[2];
    const float* y         = (const float*)d_in[3];
    const int*   inter_len = (const int*)d_in[5];
    const float* emb  = (const float*)d_in[6];
    const float* Wi_h = (const float*)d_in[7];
    const float* Wh_h = (const float*)d_in[8];
    const float* bi_h = (const float*)d_in[9];
    const float* bh_h = (const float*)d_in[10];
    const float* Wi_x = (const float*)d_in[11];
    const float* Wh_x = (const float*)d_in[12];
    const float* bi_x = (const float*)d_in[13];
    const float* bh_x = (const float*)d_in[14];
    const float* Wq = (const float*)d_in[15];
    const float* Wo = (const float*)d_in[16];
    const float* bo = (const float*)d_in[17];
    const float* W1 = (const float*)d_in[18];
    const float* b1 = (const float*)d_in[19];
    const float* W2 = (const float*)d_in[20];
    const float* b2 = (const float*)d_in[21];
    const float* W3 = (const float*)d_in[22];
    const float* b3 = (const float*)d_in[23];

    float* out = (float*)d_out;
    float* ws  = (float*)d_ws;
    // workspace (floats): pre_h 192000 | xw 393216 | mrv16 (524288 ushort =
    // 262144 float-slots) | h_x 131072  => 3.91 MB total (< proven 3.97 MB)
    float*          pre_h = ws;
    float*          xw    = ws + 192000;
    unsigned short* mrv16 = (unsigned short*)(ws + 585216);
    float*          h_x   = ws + 847360;

    precompute_tab<<<Vn + NROW, 192, 0, stream>>>(emb, Wi_h, bi_h, Wi_x, bi_x,
                                                  intra_x, y, pre_h, xw);
    gru_fused<<<1 + NSEQ / GP, 256, 0, stream>>>(pre_h, xw, inter_his, inter_len,
                                                 Wh_h, bh_h, Wi_h,
                                                 Wh_x, bh_x,
                                                 mrv16, h_x);
    attn_mlp<<<NROW, 256, 0, stream>>>(h_x, mrv16, emb, inter_r, y,
                                       Wq, Wo, bo, W1, b1, W2, b2, W3, b3, out);
}